// Round 4
// baseline (408.545 us; speedup 1.0000x reference)
//
#include <hip/hip_runtime.h>
#include <hip/hip_bf16.h>
#include <stdint.h>

// Problem constants: B=4,S=2048 -> T=8192, D=1024, H=2048, E=8, topk=2
#define T_TOK   8192
#define D_DIM   1024
#define H_DIM   2048
#define E_EXP   8
#define NP2     4096                    // interleaved w1/w2 rows = 2*H
#define BM      256                     // GEMM M-tile; expert regions 256-aligned
#define CAP     (2*T_TOK + E_EXP*BM)    // 18432 padded slots
#define MAXMB   (CAP/BM)                // 72 max m-blocks

using f32x4 = __attribute__((ext_vector_type(4))) float;
using s16x4 = __attribute__((ext_vector_type(4))) short;
using s16x8 = __attribute__((ext_vector_type(8))) short;   // 8 bf16 (MFMA A/B frag)

__device__ __forceinline__ short bf16_of(float f) {
  union { float f; unsigned u; } v; v.f = f;
  unsigned r = v.u + 0x7FFFu + ((v.u >> 16) & 1u);          // RNE
  return (short)(r >> 16);
}
__device__ __forceinline__ float f_of_bf16(short s) {
  union { unsigned u; float f; } v; v.u = ((unsigned)(unsigned short)s) << 16;
  return v.f;
}

__device__ __forceinline__ void gload16(const void* g, void* l) {
  __builtin_amdgcn_global_load_lds(
      (const __attribute__((address_space(1))) unsigned int*)g,
      (__attribute__((address_space(3))) unsigned int*)l, 16, 0, 0);
}

// ---------------- weight conversion ----------------
// w12b layout: [e][n'][k], n' = g*32 + half*16 + s -> (half?w2:w1)[e][g*16+s][k]
__global__ __launch_bounds__(256) void conv_w12(const float* __restrict__ w1,
                                                const float* __restrict__ w2,
                                                short* __restrict__ w12b) {
  int idx = blockIdx.x * 256 + threadIdx.x;        // over E*4096*256 f32x4 units
  int e = idx >> 20;
  int rem = idx & 0xFFFFF;
  int np = rem >> 8;
  int kc = rem & 255;
  int g = np >> 5, tt = np & 31, half = tt >> 4, srow = g * 16 + (tt & 15);
  const f32x4* src = (const f32x4*)(half ? w2 : w1) + ((size_t)e * H_DIM + srow) * 256 + kc;
  f32x4 v = *src;
  s16x4 o;
  o[0] = bf16_of(v[0]); o[1] = bf16_of(v[1]); o[2] = bf16_of(v[2]); o[3] = bf16_of(v[3]);
  ((s16x4*)w12b)[idx] = o;
}

__global__ __launch_bounds__(256) void conv_w3(const float* __restrict__ w3,
                                               short* __restrict__ w3b) {
  int idx = blockIdx.x * 256 + threadIdx.x;        // over E*1024*512 f32x4 units
  f32x4 v = ((const f32x4*)w3)[idx];
  s16x4 o;
  o[0] = bf16_of(v[0]); o[1] = bf16_of(v[1]); o[2] = bf16_of(v[2]); o[3] = bf16_of(v[3]);
  ((s16x4*)w3b)[idx] = o;
}

// ---------------- gating (no atomics) ----------------
__global__ __launch_bounds__(256) void gate_kernel(const float* __restrict__ x,
                                                   const float* __restrict__ gw,
                                                   int* __restrict__ tok_e,
                                                   float* __restrict__ gatew) {
  __shared__ float g[E_EXP * D_DIM];               // 32 KiB
  int tid = threadIdx.x;
  for (int i = tid; i < E_EXP * 256; i += 256)
    ((f32x4*)g)[i] = ((const f32x4*)gw)[i];
  __syncthreads();
  int w = tid >> 6, lane = tid & 63;
  int t = blockIdx.x * 4 + w;
  float acc[E_EXP] = {};
  const f32x4* xrow = (const f32x4*)(x + (size_t)t * D_DIM);
#pragma unroll
  for (int i = 0; i < 4; ++i) {
    f32x4 xv = xrow[lane + 64 * i];
#pragma unroll
    for (int e = 0; e < E_EXP; ++e) {
      f32x4 gv = ((const f32x4*)g)[e * 256 + lane + 64 * i];
      acc[e] += xv[0] * gv[0] + xv[1] * gv[1] + xv[2] * gv[2] + xv[3] * gv[3];
    }
  }
#pragma unroll
  for (int e = 0; e < E_EXP; ++e)
#pragma unroll
    for (int off = 1; off < 64; off <<= 1)
      acc[e] += __shfl_xor(acc[e], off);
  if (lane == 0) {
    int i0 = 0; float v0 = acc[0];
    for (int e = 1; e < E_EXP; ++e) if (acc[e] > v0) { v0 = acc[e]; i0 = e; }  // ties: lower idx
    int i1 = -1; float v1 = -1e30f;
    for (int e = 0; e < E_EXP; ++e) if (e != i0 && acc[e] > v1) { v1 = acc[e]; i1 = e; }
    float z = __expf(v1 - v0);
    tok_e[2 * t] = i0; tok_e[2 * t + 1] = i1;
    gatew[2 * t] = 1.f / (1.f + z); gatew[2 * t + 1] = z / (1.f + z);
  }
}

// ---------------- histogram: ballot -> LDS -> 8 atomics/block ----------
__global__ __launch_bounds__(256) void hist_kernel(const int* __restrict__ tok_e,
                                                   int* __restrict__ counts) {
  __shared__ int bc[E_EXP];
  const int tid = threadIdx.x, lane = tid & 63;
  if (tid < E_EXP) bc[tid] = 0;
  __syncthreads();
  const int4 v = ((const int4*)tok_e)[blockIdx.x * 256 + tid];   // 4 entries/thread
#pragma unroll
  for (int e = 0; e < E_EXP; ++e) {
    int cnt = __popcll(__ballot(v.x == e)) + __popcll(__ballot(v.y == e)) +
              __popcll(__ballot(v.z == e)) + __popcll(__ballot(v.w == e));
    if (lane == 0 && cnt) atomicAdd(&bc[e], cnt);
  }
  __syncthreads();
  if (tid < E_EXP && bc[tid]) atomicAdd(&counts[tid], bc[tid]);
}

// ---------------- routing metadata ----------------
__global__ void scan_kernel(const int* __restrict__ counts, int* __restrict__ off,
                            int* __restrict__ mb2e, int* __restrict__ mb2row) {
  if (threadIdx.x == 0 && blockIdx.x == 0) {
    int acc = 0, mb = 0;
    for (int e = 0; e < E_EXP; ++e) {
      off[e] = acc;
      int nb = (counts[e] + BM - 1) / BM;
      for (int b = 0; b < nb; ++b) { mb2e[mb] = e; mb2row[mb] = acc + b * BM; ++mb; }
      acc += nb * BM;
    }
    off[E_EXP] = acc;
    for (; mb < MAXMB; ++mb) mb2e[mb] = -1;
  }
}

// ---------------- assign: wave ballot-rank + block LDS aggregation ----------------
__global__ __launch_bounds__(256) void assign_kernel(const int* __restrict__ tok_e,
                                                     const int* __restrict__ off,
                                                     int* __restrict__ fill,
                                                     int* __restrict__ perm,
                                                     int* __restrict__ tok_slot) {
  __shared__ int wcnt[4][E_EXP];
  __shared__ int wbase[4][E_EXP];
  const int tid = threadIdx.x, lane = tid & 63, wid = tid >> 6;
  if (tid < 32) wcnt[tid >> 3][tid & 7] = 0;
  __syncthreads();
  const int ent = blockIdx.x * 256 + tid;          // ent = 2*t + k
  const int e = tok_e[ent];
  int myrank = 0;
#pragma unroll
  for (int e0 = 0; e0 < E_EXP; ++e0) {
    unsigned long long m = __ballot(e == e0);
    if (e == e0) {
      myrank = __popcll(m & ((1ull << lane) - 1ull));
      if (myrank == 0) wcnt[wid][e0] = __popcll(m);
    }
  }
  __syncthreads();
  if (tid < E_EXP) {
    int tot = wcnt[0][tid] + wcnt[1][tid] + wcnt[2][tid] + wcnt[3][tid];
    int base = tot ? atomicAdd(&fill[tid], tot) : 0;
#pragma unroll
    for (int w = 0; w < 4; ++w) { wbase[w][tid] = base; base += wcnt[w][tid]; }
  }
  __syncthreads();
  const int slot = off[e] + wbase[wid][e] + myrank;
  perm[slot] = ent >> 1;
  tok_slot[ent] = slot;
}

// ---------------- gather tokens -> contiguous bf16 rows per expert ----------------
__global__ __launch_bounds__(128) void gather_kernel(const float* __restrict__ x,
                                                     const int* __restrict__ off,
                                                     const int* __restrict__ counts,
                                                     const int* __restrict__ perm,
                                                     short* __restrict__ Xp) {
  int s = blockIdx.x, tid = threadIdx.x;
  int e = -1;
#pragma unroll
  for (int i = 0; i < E_EXP; ++i)
    if (s >= off[i] && s < off[i + 1]) { e = i; break; }
  bool valid = false; int t = 0;
  if (e >= 0) { int r = s - off[e]; if (r < counts[e]) { valid = true; t = perm[s]; } }
  s16x8 o;
  if (valid) {
    const f32x4* xr = (const f32x4*)(x + (size_t)t * D_DIM);
    f32x4 a = xr[tid * 2], b = xr[tid * 2 + 1];
    o[0] = bf16_of(a[0]); o[1] = bf16_of(a[1]); o[2] = bf16_of(a[2]); o[3] = bf16_of(a[3]);
    o[4] = bf16_of(b[0]); o[5] = bf16_of(b[1]); o[6] = bf16_of(b[2]); o[7] = bf16_of(b[3]);
  } else {
#pragma unroll
    for (int j = 0; j < 8; ++j) o[j] = 0;
  }
  *(s16x8*)(Xp + (size_t)s * D_DIM + tid * 8) = o;
}

// ---------------- GEMM: 256(M) x BN_(N) tile, BK=32, 8 waves, triple-buffer LDS,
// prefetch distance 2 K-tiles, counted vmcnt per K-tile (T4), and per-phase
// lockstep (T3): {ds_read || stage -> barrier -> lgkmcnt(0) -> sched_barrier ->
// setprio(1) -> MFMA cluster -> setprio(0) -> barrier}. 2 phases per K-tile.
// BN_=256: 1 block/CU (96KB LDS). BN_=128: 72KB LDS -> 2 blocks/CU (gemm3 tail fix).
template <int K, int BN_, int EPI>
__global__ __launch_bounds__(512, (BN_ == 128) ? 4 : 2)
void gemm256(const short* __restrict__ A,
             const short* __restrict__ Bw,
             const int* __restrict__ mb2e,
             const int* __restrict__ mb2row,
             const float* __restrict__ biasA,
             const float* __restrict__ biasB,
             short* __restrict__ Out) {
  constexpr int NFULL = (EPI == 0) ? NP2 : D_DIM;
  constexpr int OUTLD = (EPI == 0) ? H_DIM : D_DIM;
  constexpr int KB = K * 2;          // row bytes
  constexpr int NT = K / 32;         // K-tiles
  constexpr int NBF = BN_ / 64;      // B frags per wave (4 or 2)
  constexpr int ABYTES = 16384;      // 256 rows x 64B
  constexpr int BBYTES = BN_ * 64;
  constexpr int BUFB = ABYTES + BBYTES;
  constexpr int NB_LOADS = BN_ / 128;  // gload rounds for B (2 or 1)

  const int mb = blockIdx.y;
  const int e = mb2e[mb];
  if (e < 0) return;
  const int row0 = mb2row[mb];
  const int bn = blockIdx.x;

  __shared__ alignas(16) char lds[3 * BUFB];

  const int tid = threadIdx.x;
  const int lane = tid & 63;
  const int wid = tid >> 6;          // 0..7
  const int wr = wid >> 2;           // 0..1  (128-row half)
  const int wc = wid & 3;            // 0..3  (BN_/4-col quarter)

  const char* gA = (const char*)(A + (size_t)row0 * K);
  const char* gB = (const char*)(Bw + ((size_t)e * NFULL + (size_t)bn * BN_) * K);

  const int srow0 = tid >> 2, spq = tid & 3;

  f32x4 acc[8][NBF] = {};

  auto stageA = [&](int kt, int buf) {
#pragma unroll
    for (int r = 0; r < 2; ++r) {
      const int row = r * 128 + srow0;
      const int lq = spq ^ ((row >> 1) & 3);
      gload16(gA + (size_t)row * KB + kt * 64 + lq * 16,
              lds + buf * BUFB + r * 8192 + tid * 16);
    }
  };
  auto stageB = [&](int kt, int buf) {
#pragma unroll
    for (int r = 0; r < NB_LOADS; ++r) {
      const int row = r * 128 + srow0;
      const int lq = spq ^ ((row >> 1) & 3);
      gload16(gB + (size_t)row * KB + kt * 64 + lq * 16,
              lds + buf * BUFB + ABYTES + r * 8192 + tid * 16);
    }
  };

  // prologue: stage K-tiles 0 and 1; wait for tile0's loads (counted), barrier
  stageA(0, 0); stageB(0, 0);
  stageA(1, 1); stageB(1, 1);
  if constexpr (BN_ == 256) asm volatile("s_waitcnt vmcnt(4)" ::: "memory");
  else                      asm volatile("s_waitcnt vmcnt(3)" ::: "memory");
  __builtin_amdgcn_s_barrier();
  __builtin_amdgcn_sched_barrier(0);

  const int qsw = (((lane >> 4) ^ ((lane >> 1) & 3)) << 4);  // swizzled quarter byte
  const int arow = wr * 128 + (lane & 15);
  const int brow = wc * (BN_ / 4) + (lane & 15);

  int bc = 0;   // t % 3
  int b2 = 2;   // (t+2) % 3
  for (int t = 0; t < NT; ++t) {
    const char* bufb = lds + bc * BUFB;
    const char* pa = bufb + arow * 64 + qsw;
    const char* pb = bufb + ABYTES + brow * 64 + qsw;
    s16x8 av[4], bv[NBF];
    // ================= phase 1: A-low quadrants =================
#pragma unroll
    for (int f = 0; f < NBF; ++f) bv[f] = *(const s16x8*)(pb + f * 1024);
#pragma unroll
    for (int f = 0; f < 4; ++f) av[f] = *(const s16x8*)(pa + f * 1024);
    if (t + 2 < NT) stageA(t + 2, b2);
    __builtin_amdgcn_s_barrier();
    asm volatile("s_waitcnt lgkmcnt(0)" ::: "memory");
    __builtin_amdgcn_sched_barrier(0);
    __builtin_amdgcn_s_setprio(1);
#pragma unroll
    for (int mf = 0; mf < 4; ++mf)
#pragma unroll
      for (int nf = 0; nf < NBF; ++nf)
        acc[mf][nf] = __builtin_amdgcn_mfma_f32_16x16x32_bf16(av[mf], bv[nf], acc[mf][nf], 0, 0, 0);
    __builtin_amdgcn_s_setprio(0);
    __builtin_amdgcn_sched_barrier(0);
    __builtin_amdgcn_s_barrier();
    // ================= phase 2: A-high quadrants =================
#pragma unroll
    for (int f = 0; f < 4; ++f) av[f] = *(const s16x8*)(pa + (4 + f) * 1024);
    if (t + 2 < NT) stageB(t + 2, b2);
    __builtin_amdgcn_s_barrier();
    asm volatile("s_waitcnt lgkmcnt(0)" ::: "memory");
    __builtin_amdgcn_sched_barrier(0);
    __builtin_amdgcn_s_setprio(1);
#pragma unroll
    for (int mf = 0; mf < 4; ++mf)
#pragma unroll
      for (int nf = 0; nf < NBF; ++nf)
        acc[4 + mf][nf] = __builtin_amdgcn_mfma_f32_16x16x32_bf16(av[mf], bv[nf], acc[4 + mf][nf], 0, 0, 0);
    __builtin_amdgcn_s_setprio(0);
    __builtin_amdgcn_sched_barrier(0);
    if (t < NT - 1) {
      if (t == NT - 2)          asm volatile("s_waitcnt vmcnt(0)" ::: "memory");
      else if (BN_ == 256)      asm volatile("s_waitcnt vmcnt(4)" ::: "memory");
      else                      asm volatile("s_waitcnt vmcnt(3)" ::: "memory");
      __builtin_amdgcn_s_barrier();
      __builtin_amdgcn_sched_barrier(0);
    }
    bc = (bc == 2) ? 0 : bc + 1;
    b2 = (b2 == 2) ? 0 : b2 + 1;
  }

  // epilogue: C/D layout col=lane&15, row=(lane>>4)*4+j
  if constexpr (EPI == 0) {
#pragma unroll
    for (int mf = 0; mf < 8; ++mf) {
      const int mrow = row0 + wr * 128 + mf * 16 + ((lane >> 4) << 2);
#pragma unroll
      for (int p = 0; p < 2; ++p) {                // nf pair: 2p=w1-path, 2p+1=w2-path
        const int hcol = bn * 128 + wc * 32 + p * 16 + (lane & 15);
        const float bb1 = biasA[e * H_DIM + hcol];
        const float bb2 = biasB[e * H_DIM + hcol];
        const f32x4 a1 = acc[mf][2 * p], a2 = acc[mf][2 * p + 1];
#pragma unroll
        for (int j = 0; j < 4; ++j) {
          float x1 = a1[j] + bb1, x2 = a2[j] + bb2;
          float hv = x1 * (x2 / (1.f + __expf(-x2)));   // x1 * silu(x2)
          Out[(size_t)(mrow + j) * OUTLD + hcol] = bf16_of(hv);
        }
      }
    }
  } else {
#pragma unroll
    for (int mf = 0; mf < 8; ++mf) {
      const int mrow = row0 + wr * 128 + mf * 16 + ((lane >> 4) << 2);
#pragma unroll
      for (int nf = 0; nf < NBF; ++nf) {
        const int col = bn * BN_ + wc * (BN_ / 4) + nf * 16 + (lane & 15);
        const float bb = biasA[e * D_DIM + col];
#pragma unroll
        for (int j = 0; j < 4; ++j)
          Out[(size_t)(mrow + j) * OUTLD + col] = bf16_of(acc[mf][nf][j] + bb);
      }
    }
  }
}

// ---------------- combine: out[t] = w0*ys[slot0] + w1*ys[slot1] ----------------
__global__ __launch_bounds__(128) void combine_kernel(const short* __restrict__ ysb,
                                                      const int* __restrict__ tok_slot,
                                                      const float* __restrict__ gatew,
                                                      float* __restrict__ out) {
  int t = blockIdx.x, tid = threadIdx.x;
  int s0 = tok_slot[2 * t], s1 = tok_slot[2 * t + 1];
  float w0 = gatew[2 * t], w1 = gatew[2 * t + 1];
  s16x8 a = *(const s16x8*)(ysb + (size_t)s0 * D_DIM + tid * 8);
  s16x8 b = *(const s16x8*)(ysb + (size_t)s1 * D_DIM + tid * 8);
  float* op = out + (size_t)t * D_DIM + tid * 8;
  f32x4 o0, o1;
#pragma unroll
  for (int j = 0; j < 4; ++j) o0[j] = w0 * f_of_bf16(a[j]) + w1 * f_of_bf16(b[j]);
#pragma unroll
  for (int j = 0; j < 4; ++j) o1[j] = w0 * f_of_bf16(a[4 + j]) + w1 * f_of_bf16(b[4 + j]);
  *(f32x4*)op = o0;
  *(f32x4*)(op + 4) = o1;
}

// ---------------- launcher ----------------
extern "C" void kernel_launch(void* const* d_in, const int* in_sizes, int n_in,
                              void* d_out, int out_size, void* d_ws, size_t ws_size,
                              hipStream_t stream) {
  const float* x  = (const float*)d_in[0];
  const float* gw = (const float*)d_in[1];
  const float* w1 = (const float*)d_in[2];
  const float* b1 = (const float*)d_in[3];
  const float* w2 = (const float*)d_in[4];
  const float* b2 = (const float*)d_in[5];
  const float* w3 = (const float*)d_in[6];
  const float* b3 = (const float*)d_in[7];
  float* out = (float*)d_out;

  char* ws = (char*)d_ws;
  size_t o = 0;
  short* w12b = (short*)(ws + o); o += (size_t)E_EXP * NP2 * D_DIM * 2;      //  67,108,864
  short* w3b  = (short*)(ws + o); o += (size_t)E_EXP * D_DIM * H_DIM * 2;    //  33,554,432
  short* Xp   = (short*)(ws + o); o += (size_t)CAP * D_DIM * 2;              //  37,748,736
  short* ysb  = Xp;                 // alias: Xp dead after gemm12, ysb written by gemm3
  short* hbuf = (short*)(ws + o); o += (size_t)CAP * H_DIM * 2;              //  75,497,472
  int* meta     = (int*)(ws + o);
  int* counts   = meta;             // 8
  int* fill     = meta + 8;         // 8
  int* offv     = meta + 16;        // 9 (pad to 16)
  int* mb2e     = meta + 32;        // 72 (pad to 80)
  int* mb2row   = meta + 112;       // 72 (pad to 80)
  int* tok_e    = meta + 192;       // 2T
  int* tok_slot = tok_e + 2 * T_TOK;
  int* perm     = tok_slot + 2 * T_TOK;             // CAP
  float* gatew  = (float*)(perm + CAP);             // 2T
  const size_t ws_needed = o + (192 + 4 * T_TOK + CAP + 2 * T_TOK) * sizeof(int);
  if (ws_size < ws_needed) return;   // fail validation loudly rather than corrupt

  hipMemsetAsync(counts, 0, 16 * sizeof(int), stream);  // counts + fill

  conv_w12<<<(E_EXP * NP2 * 256) / 256, 256, 0, stream>>>(w1, w2, w12b);
  conv_w3 <<<(E_EXP * D_DIM * (H_DIM / 4)) / 256, 256, 0, stream>>>(w3, w3b);
  gate_kernel<<<T_TOK / 4, 256, 0, stream>>>(x, gw, tok_e, gatew);
  hist_kernel<<<(2 * T_TOK) / 1024, 256, 0, stream>>>(tok_e, counts);
  scan_kernel<<<1, 64, 0, stream>>>(counts, offv, mb2e, mb2row);
  assign_kernel<<<(2 * T_TOK) / 256, 256, 0, stream>>>(tok_e, offv, fill, perm, tok_slot);
  gather_kernel<<<CAP, 128, 0, stream>>>(x, offv, counts, perm, Xp);
  gemm256<D_DIM, 256, 0><<<dim3(NP2 / 256, MAXMB), 512, 0, stream>>>(Xp, w12b, mb2e, mb2row, b1, b2, hbuf);
  gemm256<H_DIM, 128, 1><<<dim3(D_DIM / 128, MAXMB), 512, 0, stream>>>(hbuf, w3b, mb2e, mb2row, b3, b3, ysb);
  combine_kernel<<<T_TOK, 128, 0, stream>>>(ysb, tok_slot, gatew, out);
}

// Round 5
// 383.477 us; speedup vs baseline: 1.0654x; 1.0654x over previous
//
#include <hip/hip_runtime.h>
#include <hip/hip_bf16.h>
#include <stdint.h>

// Problem constants: B=4,S=2048 -> T=8192, D=1024, H=2048, E=8, topk=2
#define T_TOK   8192
#define D_DIM   1024
#define H_DIM   2048
#define E_EXP   8
#define NP2     4096                    // interleaved w1/w2 rows = 2*H
#define BM      256                     // GEMM M-tile; expert regions 256-aligned
#define CAP     (2*T_TOK + E_EXP*BM)    // 18432 padded slots
#define MAXMB   (CAP/BM)                // 72 max m-blocks

using f32x4 = __attribute__((ext_vector_type(4))) float;
using s16x4 = __attribute__((ext_vector_type(4))) short;
using s16x8 = __attribute__((ext_vector_type(8))) short;   // 8 bf16 (MFMA A/B frag)

__device__ __forceinline__ short bf16_of(float f) {
  union { float f; unsigned u; } v; v.f = f;
  unsigned r = v.u + 0x7FFFu + ((v.u >> 16) & 1u);          // RNE
  return (short)(r >> 16);
}
__device__ __forceinline__ float f_of_bf16(short s) {
  union { unsigned u; float f; } v; v.u = ((unsigned)(unsigned short)s) << 16;
  return v.f;
}

__device__ __forceinline__ void gload16(const void* g, void* l) {
  __builtin_amdgcn_global_load_lds(
      (const __attribute__((address_space(1))) unsigned int*)g,
      (__attribute__((address_space(3))) unsigned int*)l, 16, 0, 0);
}

// ---------------- weight conversion ----------------
// w12b layout: [e][n'][k], n' = g*32 + half*16 + s -> (half?w2:w1)[e][g*16+s][k]
__global__ __launch_bounds__(256) void conv_w12(const float* __restrict__ w1,
                                                const float* __restrict__ w2,
                                                short* __restrict__ w12b) {
  int idx = blockIdx.x * 256 + threadIdx.x;        // over E*4096*256 f32x4 units
  int e = idx >> 20;
  int rem = idx & 0xFFFFF;
  int np = rem >> 8;
  int kc = rem & 255;
  int g = np >> 5, tt = np & 31, half = tt >> 4, srow = g * 16 + (tt & 15);
  const f32x4* src = (const f32x4*)(half ? w2 : w1) + ((size_t)e * H_DIM + srow) * 256 + kc;
  f32x4 v = *src;
  s16x4 o;
  o[0] = bf16_of(v[0]); o[1] = bf16_of(v[1]); o[2] = bf16_of(v[2]); o[3] = bf16_of(v[3]);
  ((s16x4*)w12b)[idx] = o;
}

__global__ __launch_bounds__(256) void conv_w3(const float* __restrict__ w3,
                                               short* __restrict__ w3b) {
  int idx = blockIdx.x * 256 + threadIdx.x;        // over E*1024*512 f32x4 units
  f32x4 v = ((const f32x4*)w3)[idx];
  s16x4 o;
  o[0] = bf16_of(v[0]); o[1] = bf16_of(v[1]); o[2] = bf16_of(v[2]); o[3] = bf16_of(v[3]);
  ((s16x4*)w3b)[idx] = o;
}

// ---------------- gating (no atomics) ----------------
__global__ __launch_bounds__(256) void gate_kernel(const float* __restrict__ x,
                                                   const float* __restrict__ gw,
                                                   int* __restrict__ tok_e,
                                                   float* __restrict__ gatew) {
  __shared__ float g[E_EXP * D_DIM];               // 32 KiB
  int tid = threadIdx.x;
  for (int i = tid; i < E_EXP * 256; i += 256)
    ((f32x4*)g)[i] = ((const f32x4*)gw)[i];
  __syncthreads();
  int w = tid >> 6, lane = tid & 63;
  int t = blockIdx.x * 4 + w;
  float acc[E_EXP] = {};
  const f32x4* xrow = (const f32x4*)(x + (size_t)t * D_DIM);
#pragma unroll
  for (int i = 0; i < 4; ++i) {
    f32x4 xv = xrow[lane + 64 * i];
#pragma unroll
    for (int e = 0; e < E_EXP; ++e) {
      f32x4 gv = ((const f32x4*)g)[e * 256 + lane + 64 * i];
      acc[e] += xv[0] * gv[0] + xv[1] * gv[1] + xv[2] * gv[2] + xv[3] * gv[3];
    }
  }
#pragma unroll
  for (int e = 0; e < E_EXP; ++e)
#pragma unroll
    for (int off = 1; off < 64; off <<= 1)
      acc[e] += __shfl_xor(acc[e], off);
  if (lane == 0) {
    int i0 = 0; float v0 = acc[0];
    for (int e = 1; e < E_EXP; ++e) if (acc[e] > v0) { v0 = acc[e]; i0 = e; }  // ties: lower idx
    int i1 = -1; float v1 = -1e30f;
    for (int e = 0; e < E_EXP; ++e) if (e != i0 && acc[e] > v1) { v1 = acc[e]; i1 = e; }
    float z = __expf(v1 - v0);
    tok_e[2 * t] = i0; tok_e[2 * t + 1] = i1;
    gatew[2 * t] = 1.f / (1.f + z); gatew[2 * t + 1] = z / (1.f + z);
  }
}

// ---------------- histogram: ballot -> LDS -> 8 atomics/block ----------
__global__ __launch_bounds__(256) void hist_kernel(const int* __restrict__ tok_e,
                                                   int* __restrict__ counts) {
  __shared__ int bc[E_EXP];
  const int tid = threadIdx.x, lane = tid & 63;
  if (tid < E_EXP) bc[tid] = 0;
  __syncthreads();
  const int4 v = ((const int4*)tok_e)[blockIdx.x * 256 + tid];   // 4 entries/thread
#pragma unroll
  for (int e = 0; e < E_EXP; ++e) {
    int cnt = __popcll(__ballot(v.x == e)) + __popcll(__ballot(v.y == e)) +
              __popcll(__ballot(v.z == e)) + __popcll(__ballot(v.w == e));
    if (lane == 0 && cnt) atomicAdd(&bc[e], cnt);
  }
  __syncthreads();
  if (tid < E_EXP && bc[tid]) atomicAdd(&counts[tid], bc[tid]);
}

// ---------------- routing metadata ----------------
__global__ void scan_kernel(const int* __restrict__ counts, int* __restrict__ off,
                            int* __restrict__ mb2e, int* __restrict__ mb2row) {
  if (threadIdx.x == 0 && blockIdx.x == 0) {
    int acc = 0, mb = 0;
    for (int e = 0; e < E_EXP; ++e) {
      off[e] = acc;
      int nb = (counts[e] + BM - 1) / BM;
      for (int b = 0; b < nb; ++b) { mb2e[mb] = e; mb2row[mb] = acc + b * BM; ++mb; }
      acc += nb * BM;
    }
    off[E_EXP] = acc;
    for (; mb < MAXMB; ++mb) mb2e[mb] = -1;
  }
}

// ---------------- assign: wave ballot-rank + block LDS aggregation ----------------
__global__ __launch_bounds__(256) void assign_kernel(const int* __restrict__ tok_e,
                                                     const int* __restrict__ off,
                                                     int* __restrict__ fill,
                                                     int* __restrict__ perm,
                                                     int* __restrict__ tok_slot) {
  __shared__ int wcnt[4][E_EXP];
  __shared__ int wbase[4][E_EXP];
  const int tid = threadIdx.x, lane = tid & 63, wid = tid >> 6;
  if (tid < 32) wcnt[tid >> 3][tid & 7] = 0;
  __syncthreads();
  const int ent = blockIdx.x * 256 + tid;          // ent = 2*t + k
  const int e = tok_e[ent];
  int myrank = 0;
#pragma unroll
  for (int e0 = 0; e0 < E_EXP; ++e0) {
    unsigned long long m = __ballot(e == e0);
    if (e == e0) {
      myrank = __popcll(m & ((1ull << lane) - 1ull));
      if (myrank == 0) wcnt[wid][e0] = __popcll(m);
    }
  }
  __syncthreads();
  if (tid < E_EXP) {
    int tot = wcnt[0][tid] + wcnt[1][tid] + wcnt[2][tid] + wcnt[3][tid];
    int base = tot ? atomicAdd(&fill[tid], tot) : 0;
#pragma unroll
    for (int w = 0; w < 4; ++w) { wbase[w][tid] = base; base += wcnt[w][tid]; }
  }
  __syncthreads();
  const int slot = off[e] + wbase[wid][e] + myrank;
  perm[slot] = ent >> 1;
  tok_slot[ent] = slot;
}

// ---------------- gather tokens -> contiguous bf16 rows per expert ----------------
__global__ __launch_bounds__(128) void gather_kernel(const float* __restrict__ x,
                                                     const int* __restrict__ off,
                                                     const int* __restrict__ counts,
                                                     const int* __restrict__ perm,
                                                     short* __restrict__ Xp) {
  int s = blockIdx.x, tid = threadIdx.x;
  int e = -1;
#pragma unroll
  for (int i = 0; i < E_EXP; ++i)
    if (s >= off[i] && s < off[i + 1]) { e = i; break; }
  bool valid = false; int t = 0;
  if (e >= 0) { int r = s - off[e]; if (r < counts[e]) { valid = true; t = perm[s]; } }
  s16x8 o;
  if (valid) {
    const f32x4* xr = (const f32x4*)(x + (size_t)t * D_DIM);
    f32x4 a = xr[tid * 2], b = xr[tid * 2 + 1];
    o[0] = bf16_of(a[0]); o[1] = bf16_of(a[1]); o[2] = bf16_of(a[2]); o[3] = bf16_of(a[3]);
    o[4] = bf16_of(b[0]); o[5] = bf16_of(b[1]); o[6] = bf16_of(b[2]); o[7] = bf16_of(b[3]);
  } else {
#pragma unroll
    for (int j = 0; j < 8; ++j) o[j] = 0;
  }
  *(s16x8*)(Xp + (size_t)s * D_DIM + tid * 8) = o;
}

// ---------------- GEMM: 256(M) x BN_(N) tile, BK=32, 8 waves, triple-buffer LDS,
// prefetch distance 2 K-tiles, counted vmcnt per K-tile (T4). LOOSE schedule
// (R3-proven): ONE barrier per K-tile; waves drift within the tile so one
// wave's MFMA covers another's ds_read/stage (R4's lockstep variant regressed).
// BN_=256: 96KB LDS, 1 block/CU (gemm12). BN_=128: 72KB LDS, 2 blocks/CU (gemm3).
template <int K, int BN_, int EPI>
__global__ __launch_bounds__(512, (BN_ == 128) ? 4 : 2)
void gemm256(const short* __restrict__ A,
             const short* __restrict__ Bw,
             const int* __restrict__ mb2e,
             const int* __restrict__ mb2row,
             const float* __restrict__ biasA,
             const float* __restrict__ biasB,
             short* __restrict__ Out) {
  constexpr int NFULL = (EPI == 0) ? NP2 : D_DIM;
  constexpr int OUTLD = (EPI == 0) ? H_DIM : D_DIM;
  constexpr int KB = K * 2;          // row bytes
  constexpr int NT = K / 32;         // K-tiles
  constexpr int NBF = BN_ / 64;      // B frags per wave (4 or 2)
  constexpr int ABYTES = 16384;      // 256 rows x 64B
  constexpr int BBYTES = BN_ * 64;
  constexpr int BUFB = ABYTES + BBYTES;
  constexpr int NB_LOADS = BN_ / 128;  // gload rounds for B (2 or 1)
  constexpr int INFLIGHT = 2 + NB_LOADS;  // loads/thread per K-tile (4 or 3)

  const int mb = blockIdx.y;
  const int e = mb2e[mb];
  if (e < 0) return;
  const int row0 = mb2row[mb];
  const int bn = blockIdx.x;

  __shared__ alignas(16) char lds[3 * BUFB];

  const int tid = threadIdx.x;
  const int lane = tid & 63;
  const int wid = tid >> 6;          // 0..7
  const int wr = wid >> 2;           // 0..1  (128-row half)
  const int wc = wid & 3;            // 0..3  (BN_/4-col quarter)

  const char* gA = (const char*)(A + (size_t)row0 * K);
  const char* gB = (const char*)(Bw + ((size_t)e * NFULL + (size_t)bn * BN_) * K);

  const int srow0 = tid >> 2, spq = tid & 3;

  f32x4 acc[8][NBF] = {};

  auto stageA = [&](int kt, int buf) {
#pragma unroll
    for (int r = 0; r < 2; ++r) {
      const int row = r * 128 + srow0;
      const int lq = spq ^ ((row >> 1) & 3);
      gload16(gA + (size_t)row * KB + kt * 64 + lq * 16,
              lds + buf * BUFB + r * 8192 + tid * 16);
    }
  };
  auto stageB = [&](int kt, int buf) {
#pragma unroll
    for (int r = 0; r < NB_LOADS; ++r) {
      const int row = r * 128 + srow0;
      const int lq = spq ^ ((row >> 1) & 3);
      gload16(gB + (size_t)row * KB + kt * 64 + lq * 16,
              lds + buf * BUFB + ABYTES + r * 8192 + tid * 16);
    }
  };

  // prologue: stage K-tiles 0 and 1; counted wait for tile0's loads; barrier
  stageA(0, 0); stageB(0, 0);
  stageA(1, 1); stageB(1, 1);
  if constexpr (BN_ == 256) asm volatile("s_waitcnt vmcnt(4)" ::: "memory");
  else                      asm volatile("s_waitcnt vmcnt(3)" ::: "memory");
  __builtin_amdgcn_s_barrier();
  __builtin_amdgcn_sched_barrier(0);

  const int qsw = (((lane >> 4) ^ ((lane >> 1) & 3)) << 4);  // swizzled quarter byte
  const int arow = wr * 128 + (lane & 15);
  const int brow = wc * (BN_ / 4) + (lane & 15);

  int bc = 0;   // t % 3
  int b2 = 2;   // (t+2) % 3
  for (int t = 0; t < NT; ++t) {
    const char* bufb = lds + bc * BUFB;
    const char* pa = bufb + arow * 64 + qsw;
    const char* pb = bufb + ABYTES + brow * 64 + qsw;
    s16x8 av[4], bv[NBF];
#pragma unroll
    for (int f = 0; f < NBF; ++f) bv[f] = *(const s16x8*)(pb + f * 1024);
#pragma unroll
    for (int f = 0; f < 4; ++f) av[f] = *(const s16x8*)(pa + f * 1024);
    if (t + 2 < NT) stageA(t + 2, b2);
    __builtin_amdgcn_s_setprio(1);
#pragma unroll
    for (int mf = 0; mf < 4; ++mf)
#pragma unroll
      for (int nf = 0; nf < NBF; ++nf)
        acc[mf][nf] = __builtin_amdgcn_mfma_f32_16x16x32_bf16(av[mf], bv[nf], acc[mf][nf], 0, 0, 0);
    __builtin_amdgcn_s_setprio(0);
#pragma unroll
    for (int f = 0; f < 4; ++f) av[f] = *(const s16x8*)(pa + (4 + f) * 1024);
    if (t + 2 < NT) stageB(t + 2, b2);
    __builtin_amdgcn_s_setprio(1);
#pragma unroll
    for (int mf = 0; mf < 4; ++mf)
#pragma unroll
      for (int nf = 0; nf < NBF; ++nf)
        acc[4 + mf][nf] = __builtin_amdgcn_mfma_f32_16x16x32_bf16(av[mf], bv[nf], acc[4 + mf][nf], 0, 0, 0);
    __builtin_amdgcn_s_setprio(0);

    if (t < NT - 1) {
      __builtin_amdgcn_sched_barrier(0);
      if (t == NT - 2)          asm volatile("s_waitcnt vmcnt(0)" ::: "memory");
      else if (BN_ == 256)      asm volatile("s_waitcnt vmcnt(4)" ::: "memory");
      else                      asm volatile("s_waitcnt vmcnt(3)" ::: "memory");
      __builtin_amdgcn_s_barrier();
      __builtin_amdgcn_sched_barrier(0);
    }
    bc = (bc == 2) ? 0 : bc + 1;
    b2 = (b2 == 2) ? 0 : b2 + 1;
  }

  // epilogue: C/D layout col=lane&15, row=(lane>>4)*4+j
  if constexpr (EPI == 0) {
#pragma unroll
    for (int mf = 0; mf < 8; ++mf) {
      const int mrow = row0 + wr * 128 + mf * 16 + ((lane >> 4) << 2);
#pragma unroll
      for (int p = 0; p < 2; ++p) {                // nf pair: 2p=w1-path, 2p+1=w2-path
        const int hcol = bn * 128 + wc * 32 + p * 16 + (lane & 15);
        const float bb1 = biasA[e * H_DIM + hcol];
        const float bb2 = biasB[e * H_DIM + hcol];
        const f32x4 a1 = acc[mf][2 * p], a2 = acc[mf][2 * p + 1];
#pragma unroll
        for (int j = 0; j < 4; ++j) {
          float x1 = a1[j] + bb1, x2 = a2[j] + bb2;
          float hv = x1 * (x2 / (1.f + __expf(-x2)));   // x1 * silu(x2)
          Out[(size_t)(mrow + j) * OUTLD + hcol] = bf16_of(hv);
        }
      }
    }
  } else {
#pragma unroll
    for (int mf = 0; mf < 8; ++mf) {
      const int mrow = row0 + wr * 128 + mf * 16 + ((lane >> 4) << 2);
#pragma unroll
      for (int nf = 0; nf < NBF; ++nf) {
        const int col = bn * BN_ + wc * (BN_ / 4) + nf * 16 + (lane & 15);
        const float bb = biasA[e * D_DIM + col];
#pragma unroll
        for (int j = 0; j < 4; ++j)
          Out[(size_t)(mrow + j) * OUTLD + col] = bf16_of(acc[mf][nf][j] + bb);
      }
    }
  }
}

// ---------------- combine: out[t] = w0*ys[slot0] + w1*ys[slot1] ----------------
__global__ __launch_bounds__(128) void combine_kernel(const short* __restrict__ ysb,
                                                      const int* __restrict__ tok_slot,
                                                      const float* __restrict__ gatew,
                                                      float* __restrict__ out) {
  int t = blockIdx.x, tid = threadIdx.x;
  int s0 = tok_slot[2 * t], s1 = tok_slot[2 * t + 1];
  float w0 = gatew[2 * t], w1 = gatew[2 * t + 1];
  s16x8 a = *(const s16x8*)(ysb + (size_t)s0 * D_DIM + tid * 8);
  s16x8 b = *(const s16x8*)(ysb + (size_t)s1 * D_DIM + tid * 8);
  float* op = out + (size_t)t * D_DIM + tid * 8;
  f32x4 o0, o1;
#pragma unroll
  for (int j = 0; j < 4; ++j) o0[j] = w0 * f_of_bf16(a[j]) + w1 * f_of_bf16(b[j]);
#pragma unroll
  for (int j = 0; j < 4; ++j) o1[j] = w0 * f_of_bf16(a[4 + j]) + w1 * f_of_bf16(b[4 + j]);
  *(f32x4*)op = o0;
  *(f32x4*)(op + 4) = o1;
}

// ---------------- launcher ----------------
extern "C" void kernel_launch(void* const* d_in, const int* in_sizes, int n_in,
                              void* d_out, int out_size, void* d_ws, size_t ws_size,
                              hipStream_t stream) {
  const float* x  = (const float*)d_in[0];
  const float* gw = (const float*)d_in[1];
  const float* w1 = (const float*)d_in[2];
  const float* b1 = (const float*)d_in[3];
  const float* w2 = (const float*)d_in[4];
  const float* b2 = (const float*)d_in[5];
  const float* w3 = (const float*)d_in[6];
  const float* b3 = (const float*)d_in[7];
  float* out = (float*)d_out;

  char* ws = (char*)d_ws;
  size_t o = 0;
  short* w12b = (short*)(ws + o); o += (size_t)E_EXP * NP2 * D_DIM * 2;      //  67,108,864
  short* w3b  = (short*)(ws + o); o += (size_t)E_EXP * D_DIM * H_DIM * 2;    //  33,554,432
  short* Xp   = (short*)(ws + o); o += (size_t)CAP * D_DIM * 2;              //  37,748,736
  short* ysb  = Xp;                 // alias: Xp dead after gemm12, ysb written by gemm3
  short* hbuf = (short*)(ws + o); o += (size_t)CAP * H_DIM * 2;              //  75,497,472
  int* meta     = (int*)(ws + o);
  int* counts   = meta;             // 8
  int* fill     = meta + 8;         // 8
  int* offv     = meta + 16;        // 9 (pad to 16)
  int* mb2e     = meta + 32;        // 72 (pad to 80)
  int* mb2row   = meta + 112;       // 72 (pad to 80)
  int* tok_e    = meta + 192;       // 2T
  int* tok_slot = tok_e + 2 * T_TOK;
  int* perm     = tok_slot + 2 * T_TOK;             // CAP
  float* gatew  = (float*)(perm + CAP);             // 2T
  const size_t ws_needed = o + (192 + 4 * T_TOK + CAP + 2 * T_TOK) * sizeof(int);
  if (ws_size < ws_needed) return;   // fail validation loudly rather than corrupt

  hipMemsetAsync(counts, 0, 16 * sizeof(int), stream);  // counts + fill

  conv_w12<<<(E_EXP * NP2 * 256) / 256, 256, 0, stream>>>(w1, w2, w12b);
  conv_w3 <<<(E_EXP * D_DIM * (H_DIM / 4)) / 256, 256, 0, stream>>>(w3, w3b);
  gate_kernel<<<T_TOK / 4, 256, 0, stream>>>(x, gw, tok_e, gatew);
  hist_kernel<<<(2 * T_TOK) / 1024, 256, 0, stream>>>(tok_e, counts);
  scan_kernel<<<1, 64, 0, stream>>>(counts, offv, mb2e, mb2row);
  assign_kernel<<<(2 * T_TOK) / 256, 256, 0, stream>>>(tok_e, offv, fill, perm, tok_slot);
  gather_kernel<<<CAP, 128, 0, stream>>>(x, offv, counts, perm, Xp);
  gemm256<D_DIM, 256, 0><<<dim3(NP2 / 256, MAXMB), 512, 0, stream>>>(Xp, w12b, mb2e, mb2row, b1, b2, hbuf);
  gemm256<H_DIM, 128, 1><<<dim3(D_DIM / 128, MAXMB), 512, 0, stream>>>(hbuf, w3b, mb2e, mb2row, b3, b3, ysb);
  combine_kernel<<<T_TOK, 128, 0, stream>>>(ysb, tok_slot, gatew, out);
}

// Round 6
// 378.978 us; speedup vs baseline: 1.0780x; 1.0119x over previous
//
#include <hip/hip_runtime.h>
#include <hip/hip_bf16.h>
#include <stdint.h>

// Problem constants: B=4,S=2048 -> T=8192, D=1024, H=2048, E=8, topk=2
#define T_TOK   8192
#define D_DIM   1024
#define H_DIM   2048
#define E_EXP   8
#define NP2     4096                    // interleaved w1/w2 rows = 2*H
#define BM      256                     // GEMM M-tile; expert regions 256-aligned
#define CAP     (2*T_TOK + E_EXP*BM)    // 18432 padded slots
#define MAXMB   (CAP/BM)                // 72 max m-blocks

using f32x4 = __attribute__((ext_vector_type(4))) float;
using s16x4 = __attribute__((ext_vector_type(4))) short;
using s16x8 = __attribute__((ext_vector_type(8))) short;   // 8 bf16 (MFMA A/B frag)

__device__ __forceinline__ short bf16_of(float f) {
  union { float f; unsigned u; } v; v.f = f;
  unsigned r = v.u + 0x7FFFu + ((v.u >> 16) & 1u);          // RNE
  return (short)(r >> 16);
}
__device__ __forceinline__ float f_of_bf16(short s) {
  union { unsigned u; float f; } v; v.u = ((unsigned)(unsigned short)s) << 16;
  return v.f;
}

__device__ __forceinline__ void gload16(const void* g, void* l) {
  __builtin_amdgcn_global_load_lds(
      (const __attribute__((address_space(1))) unsigned int*)g,
      (__attribute__((address_space(3))) unsigned int*)l, 16, 0, 0);
}

// ---------------- weight conversion ----------------
// w12b layout: [e][n'][k], n' = g*32 + half*16 + s -> (half?w2:w1)[e][g*16+s][k]
__global__ __launch_bounds__(256) void conv_w12(const float* __restrict__ w1,
                                                const float* __restrict__ w2,
                                                short* __restrict__ w12b) {
  int idx = blockIdx.x * 256 + threadIdx.x;        // over E*4096*256 f32x4 units
  int e = idx >> 20;
  int rem = idx & 0xFFFFF;
  int np = rem >> 8;
  int kc = rem & 255;
  int g = np >> 5, tt = np & 31, half = tt >> 4, srow = g * 16 + (tt & 15);
  const f32x4* src = (const f32x4*)(half ? w2 : w1) + ((size_t)e * H_DIM + srow) * 256 + kc;
  f32x4 v = *src;
  s16x4 o;
  o[0] = bf16_of(v[0]); o[1] = bf16_of(v[1]); o[2] = bf16_of(v[2]); o[3] = bf16_of(v[3]);
  ((s16x4*)w12b)[idx] = o;
}

__global__ __launch_bounds__(256) void conv_w3(const float* __restrict__ w3,
                                               short* __restrict__ w3b) {
  int idx = blockIdx.x * 256 + threadIdx.x;        // over E*1024*512 f32x4 units
  f32x4 v = ((const f32x4*)w3)[idx];
  s16x4 o;
  o[0] = bf16_of(v[0]); o[1] = bf16_of(v[1]); o[2] = bf16_of(v[2]); o[3] = bf16_of(v[3]);
  ((s16x4*)w3b)[idx] = o;
}

// ---------------- gating (no atomics) ----------------
__global__ __launch_bounds__(256) void gate_kernel(const float* __restrict__ x,
                                                   const float* __restrict__ gw,
                                                   int* __restrict__ tok_e,
                                                   float* __restrict__ gatew) {
  __shared__ float g[E_EXP * D_DIM];               // 32 KiB
  int tid = threadIdx.x;
  for (int i = tid; i < E_EXP * 256; i += 256)
    ((f32x4*)g)[i] = ((const f32x4*)gw)[i];
  __syncthreads();
  int w = tid >> 6, lane = tid & 63;
  int t = blockIdx.x * 4 + w;
  float acc[E_EXP] = {};
  const f32x4* xrow = (const f32x4*)(x + (size_t)t * D_DIM);
#pragma unroll
  for (int i = 0; i < 4; ++i) {
    f32x4 xv = xrow[lane + 64 * i];
#pragma unroll
    for (int e = 0; e < E_EXP; ++e) {
      f32x4 gv = ((const f32x4*)g)[e * 256 + lane + 64 * i];
      acc[e] += xv[0] * gv[0] + xv[1] * gv[1] + xv[2] * gv[2] + xv[3] * gv[3];
    }
  }
#pragma unroll
  for (int e = 0; e < E_EXP; ++e)
#pragma unroll
    for (int off = 1; off < 64; off <<= 1)
      acc[e] += __shfl_xor(acc[e], off);
  if (lane == 0) {
    int i0 = 0; float v0 = acc[0];
    for (int e = 1; e < E_EXP; ++e) if (acc[e] > v0) { v0 = acc[e]; i0 = e; }  // ties: lower idx
    int i1 = -1; float v1 = -1e30f;
    for (int e = 0; e < E_EXP; ++e) if (e != i0 && acc[e] > v1) { v1 = acc[e]; i1 = e; }
    float z = __expf(v1 - v0);
    tok_e[2 * t] = i0; tok_e[2 * t + 1] = i1;
    gatew[2 * t] = 1.f / (1.f + z); gatew[2 * t + 1] = z / (1.f + z);
  }
}

// ---------------- histogram: ballot -> LDS -> 8 atomics/block ----------
__global__ __launch_bounds__(256) void hist_kernel(const int* __restrict__ tok_e,
                                                   int* __restrict__ counts) {
  __shared__ int bc[E_EXP];
  const int tid = threadIdx.x, lane = tid & 63;
  if (tid < E_EXP) bc[tid] = 0;
  __syncthreads();
  const int4 v = ((const int4*)tok_e)[blockIdx.x * 256 + tid];   // 4 entries/thread
#pragma unroll
  for (int e = 0; e < E_EXP; ++e) {
    int cnt = __popcll(__ballot(v.x == e)) + __popcll(__ballot(v.y == e)) +
              __popcll(__ballot(v.z == e)) + __popcll(__ballot(v.w == e));
    if (lane == 0 && cnt) atomicAdd(&bc[e], cnt);
  }
  __syncthreads();
  if (tid < E_EXP && bc[tid]) atomicAdd(&counts[tid], bc[tid]);
}

// ---------------- routing metadata ----------------
__global__ void scan_kernel(const int* __restrict__ counts, int* __restrict__ off,
                            int* __restrict__ mb2e, int* __restrict__ mb2row) {
  if (threadIdx.x == 0 && blockIdx.x == 0) {
    int acc = 0, mb = 0;
    for (int e = 0; e < E_EXP; ++e) {
      off[e] = acc;
      int nb = (counts[e] + BM - 1) / BM;
      for (int b = 0; b < nb; ++b) { mb2e[mb] = e; mb2row[mb] = acc + b * BM; ++mb; }
      acc += nb * BM;
    }
    off[E_EXP] = acc;
    for (; mb < MAXMB; ++mb) mb2e[mb] = -1;
  }
}

// ---------------- assign: wave ballot-rank + block LDS aggregation ----------------
__global__ __launch_bounds__(256) void assign_kernel(const int* __restrict__ tok_e,
                                                     const int* __restrict__ off,
                                                     int* __restrict__ fill,
                                                     int* __restrict__ perm,
                                                     int* __restrict__ tok_slot) {
  __shared__ int wcnt[4][E_EXP];
  __shared__ int wbase[4][E_EXP];
  const int tid = threadIdx.x, lane = tid & 63, wid = tid >> 6;
  if (tid < 32) wcnt[tid >> 3][tid & 7] = 0;
  __syncthreads();
  const int ent = blockIdx.x * 256 + tid;          // ent = 2*t + k
  const int e = tok_e[ent];
  int myrank = 0;
#pragma unroll
  for (int e0 = 0; e0 < E_EXP; ++e0) {
    unsigned long long m = __ballot(e == e0);
    if (e == e0) {
      myrank = __popcll(m & ((1ull << lane) - 1ull));
      if (myrank == 0) wcnt[wid][e0] = __popcll(m);
    }
  }
  __syncthreads();
  if (tid < E_EXP) {
    int tot = wcnt[0][tid] + wcnt[1][tid] + wcnt[2][tid] + wcnt[3][tid];
    int base = tot ? atomicAdd(&fill[tid], tot) : 0;
#pragma unroll
    for (int w = 0; w < 4; ++w) { wbase[w][tid] = base; base += wcnt[w][tid]; }
  }
  __syncthreads();
  const int slot = off[e] + wbase[wid][e] + myrank;
  perm[slot] = ent >> 1;
  tok_slot[ent] = slot;
}

// ---------------- gather tokens -> contiguous bf16 rows per expert ----------------
__global__ __launch_bounds__(128) void gather_kernel(const float* __restrict__ x,
                                                     const int* __restrict__ off,
                                                     const int* __restrict__ counts,
                                                     const int* __restrict__ perm,
                                                     short* __restrict__ Xp) {
  int s = blockIdx.x, tid = threadIdx.x;
  int e = -1;
#pragma unroll
  for (int i = 0; i < E_EXP; ++i)
    if (s >= off[i] && s < off[i + 1]) { e = i; break; }
  bool valid = false; int t = 0;
  if (e >= 0) { int r = s - off[e]; if (r < counts[e]) { valid = true; t = perm[s]; } }
  s16x8 o;
  if (valid) {
    const f32x4* xr = (const f32x4*)(x + (size_t)t * D_DIM);
    f32x4 a = xr[tid * 2], b = xr[tid * 2 + 1];
    o[0] = bf16_of(a[0]); o[1] = bf16_of(a[1]); o[2] = bf16_of(a[2]); o[3] = bf16_of(a[3]);
    o[4] = bf16_of(b[0]); o[5] = bf16_of(b[1]); o[6] = bf16_of(b[2]); o[7] = bf16_of(b[3]);
  } else {
#pragma unroll
    for (int j = 0; j < 8; ++j) o[j] = 0;
  }
  *(s16x8*)(Xp + (size_t)s * D_DIM + tid * 8) = o;
}

// ---------------- gemm12: 256x256 tile, BK=64, 4-phase m201-style schedule ----------
// LDS kstep-major: buf{0,1} x [A_ks0|A_ks1|B_ks0|B_ks1], each unit 16KB = [256rows][64B].
// Phase p=(ks=p>>1, half=p&1): ds_read B[ks] (half==0 only, persists) + A[ks] quarter
// (rows wr*128+half*64..+63) -> barrier -> lgkmcnt(0) -> 16 MFMA -> barrier.
// Stage tile t+1 one unit/phase: p0->B_ks0, p1->A_ks0, p2->B_ks1, p3->A_ks1.
// Counted vmcnt(4) at p1 & p3 only (4 loads in flight across every barrier; each
// unit consumed >=3 phases after issue). Last tile: vmcnt(0) at p1, no p3 wait.
__global__ __launch_bounds__(512, 2)
void gemm12_k64(const short* __restrict__ A,
                const short* __restrict__ Bw,
                const int* __restrict__ mb2e,
                const int* __restrict__ mb2row,
                const float* __restrict__ b1v,
                const float* __restrict__ b2v,
                short* __restrict__ Out) {
  constexpr int K = D_DIM;           // 1024
  constexpr int NT = K / 64;         // 16 K-tiles
  constexpr int BUFB = 65536;        // 4 units x 16KB
  __shared__ alignas(16) char lds[2 * BUFB];       // 128 KiB

  const int mb = blockIdx.y;
  const int e = mb2e[mb];
  if (e < 0) return;
  const int row0 = mb2row[mb];
  const int bn = blockIdx.x;

  const int tid = threadIdx.x;
  const int lane = tid & 63;
  const int wid = tid >> 6;
  const int wr = wid >> 2, wc = wid & 3;

  const char* gA = (const char*)(A + (size_t)row0 * K);
  const char* gB = (const char*)(Bw + ((size_t)e * NP2 + (size_t)bn * 256) * K);

  // stage one 16KB unit (2 gloads/thread). dst linear; source pre-swizzled (rule 21).
  auto stage_unit = [&](const char* g, int kt, int ks, char* dst) {
#pragma unroll
    for (int r = 0; r < 2; ++r) {
      const int row = r * 128 + (tid >> 2);
      const int lq = (tid & 3) ^ ((row >> 1) & 3);
      gload16(g + (size_t)row * (K * 2) + kt * 128 + ks * 64 + lq * 16,
              dst + r * 8192 + tid * 16);
    }
  };

  f32x4 acc[8][4] = {};

  // prologue: tile0's 4 units; oldest 4 loads = {B_ks0, A_ks0}
  stage_unit(gB, 0, 0, lds + 32768);
  stage_unit(gA, 0, 0, lds + 0);
  stage_unit(gB, 0, 1, lds + 49152);
  stage_unit(gA, 0, 1, lds + 16384);
  asm volatile("s_waitcnt vmcnt(4)" ::: "memory");
  __builtin_amdgcn_s_barrier();
  __builtin_amdgcn_sched_barrier(0);

  const int qsw = (((lane >> 4) ^ ((lane >> 1) & 3)) << 4);
  const int arow = wr * 128 + (lane & 15);
  const int brow = wc * 64 + (lane & 15);

  for (int t = 0; t < NT; ++t) {
    char* cur = lds + (t & 1) * BUFB;
    char* nxt = lds + ((t + 1) & 1) * BUFB;
    const bool more = (t + 1 < NT);
    s16x8 bv[4];
#pragma unroll
    for (int p = 0; p < 4; ++p) {
      const int ks = p >> 1, half = p & 1;
      const char* abase = cur + ks * 16384;
      s16x8 av[4];
      if (half == 0) {
        const char* bbase = cur + 32768 + ks * 16384;
#pragma unroll
        for (int f = 0; f < 4; ++f)
          bv[f] = *(const s16x8*)(bbase + (size_t)(brow + f * 16) * 64 + qsw);
      }
#pragma unroll
      for (int f = 0; f < 4; ++f)
        av[f] = *(const s16x8*)(abase + (size_t)(arow + half * 64 + f * 16) * 64 + qsw);
      if (more) {
        if (p == 0)      stage_unit(gB, t + 1, 0, nxt + 32768);
        else if (p == 1) stage_unit(gA, t + 1, 0, nxt + 0);
        else if (p == 2) stage_unit(gB, t + 1, 1, nxt + 49152);
        else             stage_unit(gA, t + 1, 1, nxt + 16384);
      }
      if (p == 1) {
        if (t == NT - 1) asm volatile("s_waitcnt vmcnt(0)" ::: "memory");
        else             asm volatile("s_waitcnt vmcnt(4)" ::: "memory");
      }
      if (p == 3 && t < NT - 1) asm volatile("s_waitcnt vmcnt(4)" ::: "memory");
      __builtin_amdgcn_s_barrier();
      asm volatile("s_waitcnt lgkmcnt(0)" ::: "memory");
      __builtin_amdgcn_sched_barrier(0);
      __builtin_amdgcn_s_setprio(1);
#pragma unroll
      for (int mf2 = 0; mf2 < 4; ++mf2)
#pragma unroll
        for (int nf = 0; nf < 4; ++nf)
          acc[half * 4 + mf2][nf] =
              __builtin_amdgcn_mfma_f32_16x16x32_bf16(av[mf2], bv[nf], acc[half * 4 + mf2][nf], 0, 0, 0);
      __builtin_amdgcn_s_setprio(0);
      __builtin_amdgcn_s_barrier();
    }
  }

  // epilogue: acc[mf] -> row wr*128 + (mf>>2)*64 + (mf&3)*16; C/D col=lane&15, row+=(lane>>4)*4+j
#pragma unroll
  for (int mf = 0; mf < 8; ++mf) {
    const int mrow = row0 + wr * 128 + (mf >> 2) * 64 + (mf & 3) * 16 + ((lane >> 4) << 2);
#pragma unroll
    for (int p = 0; p < 2; ++p) {                  // nf pair: 2p=w1-path, 2p+1=w2-path
      const int hcol = bn * 128 + wc * 32 + p * 16 + (lane & 15);
      const float bb1 = b1v[e * H_DIM + hcol];
      const float bb2 = b2v[e * H_DIM + hcol];
      const f32x4 a1 = acc[mf][2 * p], a2 = acc[mf][2 * p + 1];
#pragma unroll
      for (int j = 0; j < 4; ++j) {
        float x1 = a1[j] + bb1, x2 = a2[j] + bb2;
        float hv = x1 * (x2 / (1.f + __expf(-x2)));   // x1 * silu(x2)
        Out[(size_t)(mrow + j) * H_DIM + hcol] = bf16_of(hv);
      }
    }
  }
}

// ---------------- gemm3: R3-proven loose 256x256 BK=32 schedule ----------------
template <int K, int BN_, int EPI>
__global__ __launch_bounds__(512, (BN_ == 128) ? 4 : 2)
void gemm256(const short* __restrict__ A,
             const short* __restrict__ Bw,
             const int* __restrict__ mb2e,
             const int* __restrict__ mb2row,
             const float* __restrict__ biasA,
             const float* __restrict__ biasB,
             short* __restrict__ Out) {
  constexpr int NFULL = (EPI == 0) ? NP2 : D_DIM;
  constexpr int OUTLD = (EPI == 0) ? H_DIM : D_DIM;
  constexpr int KB = K * 2;          // row bytes
  constexpr int NT = K / 32;         // K-tiles
  constexpr int NBF = BN_ / 64;      // B frags per wave
  constexpr int ABYTES = 16384;
  constexpr int BBYTES = BN_ * 64;
  constexpr int BUFB = ABYTES + BBYTES;
  constexpr int NB_LOADS = BN_ / 128;

  const int mb = blockIdx.y;
  const int e = mb2e[mb];
  if (e < 0) return;
  const int row0 = mb2row[mb];
  const int bn = blockIdx.x;

  __shared__ alignas(16) char lds[3 * BUFB];

  const int tid = threadIdx.x;
  const int lane = tid & 63;
  const int wid = tid >> 6;
  const int wr = wid >> 2;
  const int wc = wid & 3;

  const char* gA = (const char*)(A + (size_t)row0 * K);
  const char* gB = (const char*)(Bw + ((size_t)e * NFULL + (size_t)bn * BN_) * K);

  const int srow0 = tid >> 2, spq = tid & 3;

  f32x4 acc[8][NBF] = {};

  auto stageA = [&](int kt, int buf) {
#pragma unroll
    for (int r = 0; r < 2; ++r) {
      const int row = r * 128 + srow0;
      const int lq = spq ^ ((row >> 1) & 3);
      gload16(gA + (size_t)row * KB + kt * 64 + lq * 16,
              lds + buf * BUFB + r * 8192 + tid * 16);
    }
  };
  auto stageB = [&](int kt, int buf) {
#pragma unroll
    for (int r = 0; r < NB_LOADS; ++r) {
      const int row = r * 128 + srow0;
      const int lq = spq ^ ((row >> 1) & 3);
      gload16(gB + (size_t)row * KB + kt * 64 + lq * 16,
              lds + buf * BUFB + ABYTES + r * 8192 + tid * 16);
    }
  };

  stageA(0, 0); stageB(0, 0);
  stageA(1, 1); stageB(1, 1);
  if constexpr (BN_ == 256) asm volatile("s_waitcnt vmcnt(4)" ::: "memory");
  else                      asm volatile("s_waitcnt vmcnt(3)" ::: "memory");
  __builtin_amdgcn_s_barrier();
  __builtin_amdgcn_sched_barrier(0);

  const int qsw = (((lane >> 4) ^ ((lane >> 1) & 3)) << 4);
  const int arow = wr * 128 + (lane & 15);
  const int brow = wc * (BN_ / 4) + (lane & 15);

  int bc = 0;
  int b2 = 2;
  for (int t = 0; t < NT; ++t) {
    const char* bufb = lds + bc * BUFB;
    const char* pa = bufb + arow * 64 + qsw;
    const char* pb = bufb + ABYTES + brow * 64 + qsw;
    s16x8 av[4], bv[NBF];
#pragma unroll
    for (int f = 0; f < NBF; ++f) bv[f] = *(const s16x8*)(pb + f * 1024);
#pragma unroll
    for (int f = 0; f < 4; ++f) av[f] = *(const s16x8*)(pa + f * 1024);
    if (t + 2 < NT) stageA(t + 2, b2);
    __builtin_amdgcn_s_setprio(1);
#pragma unroll
    for (int mf = 0; mf < 4; ++mf)
#pragma unroll
      for (int nf = 0; nf < NBF; ++nf)
        acc[mf][nf] = __builtin_amdgcn_mfma_f32_16x16x32_bf16(av[mf], bv[nf], acc[mf][nf], 0, 0, 0);
    __builtin_amdgcn_s_setprio(0);
#pragma unroll
    for (int f = 0; f < 4; ++f) av[f] = *(const s16x8*)(pa + (4 + f) * 1024);
    if (t + 2 < NT) stageB(t + 2, b2);
    __builtin_amdgcn_s_setprio(1);
#pragma unroll
    for (int mf = 0; mf < 4; ++mf)
#pragma unroll
      for (int nf = 0; nf < NBF; ++nf)
        acc[4 + mf][nf] = __builtin_amdgcn_mfma_f32_16x16x32_bf16(av[mf], bv[nf], acc[4 + mf][nf], 0, 0, 0);
    __builtin_amdgcn_s_setprio(0);

    if (t < NT - 1) {
      __builtin_amdgcn_sched_barrier(0);
      if (t == NT - 2)          asm volatile("s_waitcnt vmcnt(0)" ::: "memory");
      else if (BN_ == 256)      asm volatile("s_waitcnt vmcnt(4)" ::: "memory");
      else                      asm volatile("s_waitcnt vmcnt(3)" ::: "memory");
      __builtin_amdgcn_s_barrier();
      __builtin_amdgcn_sched_barrier(0);
    }
    bc = (bc == 2) ? 0 : bc + 1;
    b2 = (b2 == 2) ? 0 : b2 + 1;
  }

  if constexpr (EPI == 0) {
#pragma unroll
    for (int mf = 0; mf < 8; ++mf) {
      const int mrow = row0 + wr * 128 + mf * 16 + ((lane >> 4) << 2);
#pragma unroll
      for (int p = 0; p < 2; ++p) {
        const int hcol = bn * 128 + wc * 32 + p * 16 + (lane & 15);
        const float bb1 = biasA[e * H_DIM + hcol];
        const float bb2 = biasB[e * H_DIM + hcol];
        const f32x4 a1 = acc[mf][2 * p], a2 = acc[mf][2 * p + 1];
#pragma unroll
        for (int j = 0; j < 4; ++j) {
          float x1 = a1[j] + bb1, x2 = a2[j] + bb2;
          float hv = x1 * (x2 / (1.f + __expf(-x2)));
          Out[(size_t)(mrow + j) * OUTLD + hcol] = bf16_of(hv);
        }
      }
    }
  } else {
#pragma unroll
    for (int mf = 0; mf < 8; ++mf) {
      const int mrow = row0 + wr * 128 + mf * 16 + ((lane >> 4) << 2);
#pragma unroll
      for (int nf = 0; nf < NBF; ++nf) {
        const int col = bn * BN_ + wc * (BN_ / 4) + nf * 16 + (lane & 15);
        const float bb = biasA[e * D_DIM + col];
#pragma unroll
        for (int j = 0; j < 4; ++j)
          Out[(size_t)(mrow + j) * OUTLD + col] = bf16_of(acc[mf][nf][j] + bb);
      }
    }
  }
}

// ---------------- combine: out[t] = w0*ys[slot0] + w1*ys[slot1] ----------------
__global__ __launch_bounds__(128) void combine_kernel(const short* __restrict__ ysb,
                                                      const int* __restrict__ tok_slot,
                                                      const float* __restrict__ gatew,
                                                      float* __restrict__ out) {
  int t = blockIdx.x, tid = threadIdx.x;
  int s0 = tok_slot[2 * t], s1 = tok_slot[2 * t + 1];
  float w0 = gatew[2 * t], w1 = gatew[2 * t + 1];
  s16x8 a = *(const s16x8*)(ysb + (size_t)s0 * D_DIM + tid * 8);
  s16x8 b = *(const s16x8*)(ysb + (size_t)s1 * D_DIM + tid * 8);
  float* op = out + (size_t)t * D_DIM + tid * 8;
  f32x4 o0, o1;
#pragma unroll
  for (int j = 0; j < 4; ++j) o0[j] = w0 * f_of_bf16(a[j]) + w1 * f_of_bf16(b[j]);
#pragma unroll
  for (int j = 0; j < 4; ++j) o1[j] = w0 * f_of_bf16(a[4 + j]) + w1 * f_of_bf16(b[4 + j]);
  *(f32x4*)op = o0;
  *(f32x4*)(op + 4) = o1;
}

// ---------------- launcher ----------------
extern "C" void kernel_launch(void* const* d_in, const int* in_sizes, int n_in,
                              void* d_out, int out_size, void* d_ws, size_t ws_size,
                              hipStream_t stream) {
  const float* x  = (const float*)d_in[0];
  const float* gw = (const float*)d_in[1];
  const float* w1 = (const float*)d_in[2];
  const float* b1 = (const float*)d_in[3];
  const float* w2 = (const float*)d_in[4];
  const float* b2 = (const float*)d_in[5];
  const float* w3 = (const float*)d_in[6];
  const float* b3 = (const float*)d_in[7];
  float* out = (float*)d_out;

  char* ws = (char*)d_ws;
  size_t o = 0;
  short* w12b = (short*)(ws + o); o += (size_t)E_EXP * NP2 * D_DIM * 2;      //  67,108,864
  short* w3b  = (short*)(ws + o); o += (size_t)E_EXP * D_DIM * H_DIM * 2;    //  33,554,432
  short* Xp   = (short*)(ws + o); o += (size_t)CAP * D_DIM * 2;              //  37,748,736
  short* ysb  = Xp;                 // alias: Xp dead after gemm12, ysb written by gemm3
  short* hbuf = (short*)(ws + o); o += (size_t)CAP * H_DIM * 2;              //  75,497,472
  int* meta     = (int*)(ws + o);
  int* counts   = meta;             // 8
  int* fill     = meta + 8;         // 8
  int* offv     = meta + 16;        // 9 (pad to 16)
  int* mb2e     = meta + 32;        // 72 (pad to 80)
  int* mb2row   = meta + 112;       // 72 (pad to 80)
  int* tok_e    = meta + 192;       // 2T
  int* tok_slot = tok_e + 2 * T_TOK;
  int* perm     = tok_slot + 2 * T_TOK;             // CAP
  float* gatew  = (float*)(perm + CAP);             // 2T
  const size_t ws_needed = o + (192 + 4 * T_TOK + CAP + 2 * T_TOK) * sizeof(int);
  if (ws_size < ws_needed) return;   // fail validation loudly rather than corrupt

  hipMemsetAsync(counts, 0, 16 * sizeof(int), stream);  // counts + fill

  conv_w12<<<(E_EXP * NP2 * 256) / 256, 256, 0, stream>>>(w1, w2, w12b);
  conv_w3 <<<(E_EXP * D_DIM * (H_DIM / 4)) / 256, 256, 0, stream>>>(w3, w3b);
  gate_kernel<<<T_TOK / 4, 256, 0, stream>>>(x, gw, tok_e, gatew);
  hist_kernel<<<(2 * T_TOK) / 1024, 256, 0, stream>>>(tok_e, counts);
  scan_kernel<<<1, 64, 0, stream>>>(counts, offv, mb2e, mb2row);
  assign_kernel<<<(2 * T_TOK) / 256, 256, 0, stream>>>(tok_e, offv, fill, perm, tok_slot);
  gather_kernel<<<CAP, 128, 0, stream>>>(x, offv, counts, perm, Xp);
  gemm12_k64<<<dim3(NP2 / 256, MAXMB), 512, 0, stream>>>(Xp, w12b, mb2e, mb2row, b1, b2, hbuf);
  gemm256<H_DIM, 256, 1><<<dim3(D_DIM / 256, MAXMB), 512, 0, stream>>>(hbuf, w3b, mb2e, mb2row, b3, b3, ysb);
  combine_kernel<<<T_TOK, 128, 0, stream>>>(ysb, tok_slot, gatew, out);
}